// Round 9
// baseline (358.529 us; speedup 1.0000x reference)
//
#include <hip/hip_runtime.h>
#include <cmath>

#define NDOF 7
#define HID  256
#define SPW  8            // samples per workgroup
#define NCOL 64           // 8 primal cols (0..7) + 56 tangent cols (8 + s*7 + d)
#define SWZ(c) (((c) & 7) << 3)

typedef __bf16 bf16x8 __attribute__((ext_vector_type(8)));
typedef float  f32x4  __attribute__((ext_vector_type(4)));

// ws layout (bf16 elems): W1b@0 (65536), W2b@65536, Whb@131072 (48x256), W0b@143360 (256x32 K-padded)
#define OFF_W2 65536
#define OFF_WH 131072
#define OFF_W0 143360
#define WS_TOT 151552

__device__ __forceinline__ float softplus_fast(float x){
    float e = __expf(-fabsf(x));
    return fmaxf(x, 0.0f) + __logf(1.0f + e);
}
__device__ __forceinline__ float sigmoid_fast(float x){
    float e  = __expf(-fabsf(x));
    float rc = 1.0f / (1.0f + e);
    return (x >= 0.0f) ? rc : e * rc;
}
__device__ __forceinline__ float tanh_fast(float y){
    float e2 = __expf(-2.0f * fabsf(y));
    float t  = (1.0f - e2) / (1.0f + e2);
    return (y >= 0.0f) ? t : -t;
}
__device__ __forceinline__ unsigned bf16bits(float x){
    union { float f; unsigned u; } v; v.f = x;
    unsigned lsb = (v.u >> 16) & 1;
    return ((v.u + 0x7fffu + lsb) >> 16) & 0xffffu;
}

__global__ void convert_weights(const float* __restrict__ W1, const float* __restrict__ W2,
                                const float* __restrict__ Wg, const float* __restrict__ Wld,
                                const float* __restrict__ Wlt, const float* __restrict__ W0,
                                __bf16* __restrict__ ws)
{
    int i = blockIdx.x * 256 + threadIdx.x;
    if (i < OFF_W2)        ws[i] = (__bf16)W1[i];
    else if (i < OFF_WH)   ws[i] = (__bf16)W2[i - OFF_W2];
    else if (i < OFF_W0) {
        int j = i - OFF_WH;
        int r = j >> 8, k = j & 255;
        float v = 0.0f;
        if (r < 7)       v = Wg [r * HID + k];
        else if (r < 14) v = Wld[(r - 7) * HID + k];
        else if (r < 35) v = Wlt[(r - 14) * HID + k];
        ws[i] = (__bf16)v;
    } else if (i < WS_TOT) {
        int j = i - OFF_W0;
        int r = j >> 5, k = j & 31;
        ws[i] = (__bf16)((k < 7) ? W0[r * 7 + k] : 0.0f);
    }
}

// One MLP layer, N-split into two column halves (cols 0-31, 32-63).
// acc is [4 mi][2 ni] = 32 VGPR (half of the old 64) -> 5 waves/SIMD occupancy.
// Half A (owns the 8 primal cols) computes h/sigmoid and packs sg as bf16 pairs;
// half B reuses them. Column halves are read/write disjoint, so one barrier per
// half (after its K-loop) is the only sync; it also fences the previous layer.
// K-loop unroll 1 on purpose: staging+acc must stay <= 102 VGPR (512/5).
template<int KK>
__device__ __forceinline__ void mlp_layer(
    const __bf16* __restrict__ Wb, int astride, const float* __restrict__ bp,
    __bf16* Xs, int w, int lo, int hi, const int* srcl, bool prim)
{
    unsigned pa[4], pb[4];     // sg[0..3] per mi, packed 2x(bf16,bf16)
    float    h[4][4];          // softplus per mi/r (used only in half A prim write)

    #pragma unroll
    for (int nh = 0; nh < 2; ++nh){
        f32x4 acc[4][2];
        #pragma unroll
        for (int mi = 0; mi < 4; ++mi)
            #pragma unroll
            for (int j = 0; j < 2; ++j) acc[mi][j] = (f32x4){0.f,0.f,0.f,0.f};

        #pragma unroll 1
        for (int kk = 0; kk < KK; ++kk){
            const int k0 = kk * 32 + hi * 8;
            bf16x8 a[4], bfr[2];
            #pragma unroll
            for (int mi = 0; mi < 4; ++mi)
                a[mi] = *reinterpret_cast<const bf16x8*>(Wb + (w * 64 + mi * 16 + lo) * astride + k0);
            #pragma unroll
            for (int j = 0; j < 2; ++j){
                int col = (nh * 2 + j) * 16 + lo;
                bfr[j] = *reinterpret_cast<const bf16x8*>(Xs + col * HID + (k0 ^ SWZ(col)));
            }
            #pragma unroll
            for (int mi = 0; mi < 4; ++mi)
                #pragma unroll
                for (int j = 0; j < 2; ++j)
                    acc[mi][j] = __builtin_amdgcn_mfma_f32_16x16x32_bf16(a[mi], bfr[j], acc[mi][j], 0, 0, 0);
        }
        __syncthreads();   // all reads of this half's cols done; also fences prev layer's writes

        #pragma unroll
        for (int mi = 0; mi < 4; ++mi){
            const int row0 = w * 64 + mi * 16 + hi * 4;
            if (nh == 0){
                float4 b4 = *reinterpret_cast<const float4*>(bp + row0);
                float sg[4];
                #pragma unroll
                for (int r = 0; r < 4; ++r){
                    float z  = acc[mi][0][r] + ((const float*)&b4)[r];
                    float e  = __expf(-fabsf(z));
                    float rc = 1.0f / (1.0f + e);
                    h[mi][r] = fmaxf(z, 0.0f) + __logf(1.0f + e);
                    sg[r] = (z >= 0.0f) ? rc : e * rc;
                }
                pa[mi] = bf16bits(sg[0]) | (bf16bits(sg[1]) << 16);
                pb[mi] = bf16bits(sg[2]) | (bf16bits(sg[3]) << 16);
            }
            #pragma unroll
            for (int j = 0; j < 2; ++j){
                const int ni  = nh * 2 + j;
                const int col = ni * 16 + lo;
                unsigned g01 = __shfl(pa[mi], srcl[ni]);
                unsigned g23 = __shfl(pb[mi], srcl[ni]);
                float sgf[4];
                { union { unsigned u; float f; } t;
                  t.u = g01 << 16;          sgf[0] = t.f;
                  t.u = g01 & 0xffff0000u;  sgf[1] = t.f;
                  t.u = g23 << 16;          sgf[2] = t.f;
                  t.u = g23 & 0xffff0000u;  sgf[3] = t.f; }
                union { uint2 u2; __bf16 b[4]; } pk;
                #pragma unroll
                for (int r = 0; r < 4; ++r){
                    float v = (ni == 0 && prim) ? h[mi][r] : sgf[r] * acc[mi][j][r];
                    pk.b[r] = (__bf16)v;
                }
                *reinterpret_cast<uint2*>(Xs + col * HID + (row0 ^ SWZ(col))) = pk.u2;
            }
        }
        // no trailing barrier: the other half's cols are untouched by this epilogue,
        // and the next half/layer K-loop barrier provides the cross-wave fence.
    }
}

__launch_bounds__(256, 5)
__global__ void dln_main(
    const float* __restrict__ q,  const float* __restrict__ qd, const float* __restrict__ qdd,
    const float* __restrict__ b0, const float* __restrict__ b1, const float* __restrict__ b2,
    const float* __restrict__ bg, const float* __restrict__ bld, const float* __restrict__ blt,
    const float* __restrict__ fd, const float* __restrict__ fc,
    const float* __restrict__ fs, const float* __restrict__ fv,
    const __bf16* __restrict__ wsb,
    float* __restrict__ out, int Btot)
{
    __shared__ __align__(16) unsigned char LDSB[32768];
    __bf16* Xs = (__bf16*)LDSB;

    const int tid = threadIdx.x;
    const int w   = tid >> 6;
    const int l   = tid & 63;
    const int lo  = l & 15;
    const int hi  = l >> 4;
    const int s0g = blockIdx.x * SPW;
    const bool prim = (lo < 8);

    int srcl[4];
    #pragma unroll
    for (int ni = 0; ni < 4; ++ni){
        int col  = ni * 16 + lo;
        int s    = (col < 8) ? col : (col - 8) / 7;
        srcl[ni] = (l & ~15) | s;
    }

    // ---- B0 = [q | I]: zero phys k 0..63 of each col (SWZ(7) keeps logical k<32 within 0..63) ----
    {
        int col = tid >> 2, part = tid & 3;
        uint4 z4 = {0,0,0,0};
        *reinterpret_cast<uint4*>(Xs + col * HID + part * 16)     = z4;
        *reinterpret_cast<uint4*>(Xs + col * HID + part * 16 + 8) = z4;
    }
    __syncthreads();
    if (tid < 56){
        int s = tid / 7, d = tid - s * 7;
        Xs[s * HID + (d ^ SWZ(s))] = (__bf16)q[(s0g + s) * NDOF + d];
        int c = 8 + s * 7 + d;
        Xs[c * HID + (d ^ SWZ(c))] = (__bf16)1.0f;
    }
    __syncthreads();

    // ---- 3 MLP layers ----
    mlp_layer<1>(wsb + OFF_W0, 32,  b0, Xs, w, lo, hi, srcl, prim);
    mlp_layer<8>(wsb,          HID, b1, Xs, w, lo, hi, srcl, prim);
    mlp_layer<8>(wsb + OFF_W2, HID, b2, Xs, w, lo, hi, srcl, prim);
    __syncthreads();           // fence last epilogue writes before heads read all cols

    // ---- heads: [48x256] @ X -> registers (waves 0..2) ----
    f32x4 hacc[4];
    #pragma unroll
    for (int ni = 0; ni < 4; ++ni) hacc[ni] = (f32x4){0.f,0.f,0.f,0.f};
    if (w < 3){
        const __bf16* Wh = wsb + OFF_WH;
        #pragma unroll 2
        for (int kk = 0; kk < 8; ++kk){
            const int k0 = kk * 32 + hi * 8;
            bf16x8 a = *reinterpret_cast<const bf16x8*>(Wh + (w * 16 + lo) * HID + k0);
            #pragma unroll
            for (int ni = 0; ni < 4; ++ni){
                int col = ni * 16 + lo;
                bf16x8 bfr = *reinterpret_cast<const bf16x8*>(Xs + col * HID + (k0 ^ SWZ(col)));
                hacc[ni] = __builtin_amdgcn_mfma_f32_16x16x32_bf16(a, bfr, hacc[ni], 0, 0, 0);
            }
        }
    }
    __syncthreads();            // Xs fully read; region becomes SCRT + tail scratch

    // SCRT[col][row], stride 41 f32 (transposed head outputs)
    float* SCRT = (float*)LDSB;                     // 64*41*4 = 10496 B
    float* SGb  = (float*)(LDSB + 10496);           // [8][8]   sigmoid(Ld_raw)
    float* UV   = (float*)(LDSB + 10752);           // [8][16]: u@0..6, w2@8..14
    float* LL   = (float*)(LDSB + 11264);           // [8][52]: L matrix rows

    if (w < 3){
        #pragma unroll
        for (int ni = 0; ni < 4; ++ni)
            #pragma unroll
            for (int r = 0; r < 4; ++r){
                int row = w * 16 + hi * 4 + r;
                if (row < 35) SCRT[(ni * 16 + lo) * 41 + row] = hacc[ni][r];
            }
    }
    __syncthreads();

    // ---- analytic tail: lane (r,c) parallel, 49 active lanes/wave, 2 samples/wave ----
    const bool t49 = (l < 49);
    const int  tt  = t49 ? l : 0;
    const int  r   = tt / 7;
    const int  c   = tt - r * 7;
    const int  B   = Btot;
    float* oH = out + (size_t)B * 7;
    float* oC = out + (size_t)B * 56;
    float* oG = out + (size_t)B * 63;
    float* oF = out + (size_t)B * 70;
    float* oL = out + (size_t)B * 77;

    for (int p = 0; p < 2; ++p){
        const int ss = p * 4 + w;
        const int Sg = __builtin_amdgcn_readfirstlane(s0g + ss);

        // qdv[] only indexed with compile-time constants (unrolled loops);
        // lane-dependent values are direct global loads (L1-cached).
        float qdv[7];
        #pragma unroll
        for (int d = 0; d < 7; ++d) qdv[d] = qd[Sg * 7 + d];
        const float qd_r  = qd [Sg * 7 + r];
        const float qd_c  = qd [Sg * 7 + c];
        const float qdd_c = qdd[Sg * 7 + c];

        const int colP  = ss * 41;
        const int tri_r = (r * (r - 1)) >> 1;

        float ldraw = SCRT[colP + 7 + r] + bld[r];
        float sg_r  = sigmoid_fast(ldraw);
        float Lrr   = softplus_fast(ldraw) + 1e-3f;
        float Lij   = 0.f;
        if (c < r)       Lij = SCRT[colP + 14 + tri_r + c] + blt[tri_r + c];
        else if (c == r) Lij = Lrr;

        if (t49)           LL[ss * 52 + tt] = Lij;
        if (t49 && r == c) SGb[ss * 8 + r]  = sg_r;

        // u[b] = sum_a qd_a L[a][b]  (reduce over r, result at r==0 lanes l=c)
        float ux = qd_r * Lij;
        { float xs;
          xs = __shfl(ux, l + 7);  ux += (r + 1 <= 6) ? xs : 0.f;
          xs = __shfl(ux, l + 14); ux += (r + 2 <= 6) ? xs : 0.f;
          xs = __shfl(ux, l + 28); ux += (r + 4 <= 6) ? xs : 0.f; }
        if (t49 && r == 0) UV[ss * 16 + c] = ux;

        asm volatile("s_waitcnt lgkmcnt(0)" ::: "memory");
        __builtin_amdgcn_sched_barrier(0);

        float sgv[7];
        #pragma unroll
        for (int jj = 0; jj < 7; ++jj) sgv[jj] = SGb[ss * 8 + jj];

        // v[r][c] = sum_jj qd_jj LDQ(jj, r, c)
        const int colT = (8 + ss * 7 + c) * 41;
        float v = 0.f;
        #pragma unroll
        for (int jj = 0; jj < 7; ++jj){
            constexpr int triT[7] = {0,0,1,3,6,10,15};
            int   row = (jj == r) ? (7 + jj) : (14 + triT[jj] + r);
            float x   = SCRT[colT + row];
            float val = (jj == r) ? sgv[jj] * x : ((jj > r) ? x : 0.f);
            v = fmaf(qdv[jj], val, v);
        }

        // ldt[r][c] = sum_cc LDQ(r, c, cc) qd_cc
        {
            int   rowF   = (r == c) ? (7 + r) : (14 + tri_r + c);
            float scaleF = (r == c) ? sg_r : ((r > c) ? 1.f : 0.f);
            float acc2 = 0.f;
            #pragma unroll
            for (int cc = 0; cc < 7; ++cc)
                acc2 = fmaf(qdv[cc], SCRT[(8 + ss * 7 + cc) * 41 + rowF], acc2);
            float ldt = acc2 * scaleF;

            // w2[k=r] = sum_c v[r][c] qd_c  (reduce over c, result at c==0 lanes l=7r)
            float wx = v * qd_c;
            { float xs;
              xs = __shfl(wx, l + 1); wx += (c + 1 <= 6) ? xs : 0.f;
              xs = __shfl(wx, l + 2); wx += (c + 2 <= 6) ? xs : 0.f;
              xs = __shfl(wx, l + 4); wx += (c + 4 <= 6) ? xs : 0.f; }
            if (t49 && c == 0) UV[ss * 16 + 8 + r] = wx;

            asm volatile("s_waitcnt lgkmcnt(0)" ::: "memory");
            __builtin_amdgcn_sched_barrier(0);

            float u_c  = UV[ss * 16 + c];
            float u_r  = UV[ss * 16 + r];
            float w2_c = UV[ss * 16 + 8 + c];

            // qh[i=c] = sum_m u[m] v[m][i]  (reduce over r, result at r==0 lanes l=c)
            float qx = u_r * v;
            { float xs;
              xs = __shfl(qx, l + 7);  qx += (r + 1 <= 6) ? xs : 0.f;
              xs = __shfl(qx, l + 14); qx += (r + 2 <= 6) ? xs : 0.f;
              xs = __shfl(qx, l + 28); qx += (r + 4 <= 6) ? xs : 0.f; }

            // c1[i=r] = sum_k L[r][k] w2[k] + ldt[r][k] u[k]  (reduce over c)
            float cx = Lij * w2_c + ldt * u_c;
            { float xs;
              xs = __shfl(cx, l + 1); cx += (c + 1 <= 6) ? xs : 0.f;
              xs = __shfl(cx, l + 2); cx += (c + 2 <= 6) ? xs : 0.f;
              xs = __shfl(cx, l + 4); cx += (c + 4 <= 6) ? xs : 0.f; }

            // hm[r][c] = sum_k L[r][k] L[c][k]
            float hm = 0.f;
            #pragma unroll
            for (int k = 0; k < 7; ++k)
                hm = fmaf(LL[ss * 52 + r * 7 + k], LL[ss * 52 + c * 7 + k], hm);

            // tau partial: sum_j hm[r][j] qdd_j  (reduce over c)
            float tx = hm * qdd_c;
            { float xs;
              xs = __shfl(tx, l + 1); tx += (c + 1 <= 6) ? xs : 0.f;
              xs = __shfl(tx, l + 2); tx += (c + 2 <= 6) ? xs : 0.f;
              xs = __shfl(tx, l + 4); tx += (c + 4 <= 6) ? xs : 0.f; }

            float qh_r = __shfl(qx, r);      // qh[r] lives at lane l=r
            float gv   = SCRT[colP + r] + bg[r];
            float fvc  = fmaxf(fv[r], 1e-3f);
            float tf   = (fc[r] + fs[r] * __expf(-qd_r * qd_r / fvc)) * tanh_fast(100.0f * qd_r) + fd[r] * qd_r;
            float cfin = cx - qh_r;
            float tau  = cfin + gv + tf + tx;

            if (t49) oH[(size_t)Sg * 49 + tt] = hm;
            if (t49 && c == 0){
                out[Sg * 7 + r] = tau;
                oC[Sg * 7 + r]  = cfin;
                oG[Sg * 7 + r]  = gv;
                oF[Sg * 7 + r]  = tf;
                oL[Sg * 7 + r]  = ldraw;
            }
        }
    }
}

extern "C" void kernel_launch(void* const* d_in, const int* in_sizes, int n_in,
                              void* d_out, int out_size, void* d_ws, size_t ws_size,
                              hipStream_t stream) {
    const float* q   = (const float*)d_in[0];
    const float* qd  = (const float*)d_in[1];
    const float* qdd = (const float*)d_in[2];
    const float* W0  = (const float*)d_in[3];
    const float* b0  = (const float*)d_in[4];
    const float* W1  = (const float*)d_in[5];
    const float* b1  = (const float*)d_in[6];
    const float* W2  = (const float*)d_in[7];
    const float* b2  = (const float*)d_in[8];
    const float* Wg  = (const float*)d_in[9];
    const float* bg  = (const float*)d_in[10];
    const float* Wld = (const float*)d_in[11];
    const float* bld = (const float*)d_in[12];
    const float* Wlt = (const float*)d_in[13];
    const float* blt = (const float*)d_in[14];
    const float* fd  = (const float*)d_in[15];
    const float* fc  = (const float*)d_in[16];
    const float* fs  = (const float*)d_in[17];
    const float* fv  = (const float*)d_in[18];

    const int Btot = in_sizes[0] / NDOF;      // 32768
    __bf16* wsb = (__bf16*)d_ws;

    convert_weights<<<dim3(WS_TOT / 256), dim3(256), 0, stream>>>(W1, W2, Wg, Wld, Wlt, W0, wsb);
    dln_main<<<dim3(Btot / SPW), dim3(256), 0, stream>>>(q, qd, qdd, b0, b1, b2,
                                                         bg, bld, blt,
                                                         fd, fc, fs, fv,
                                                         wsb, (float*)d_out, Btot);
}

// Round 10
// 267.433 us; speedup vs baseline: 1.3406x; 1.3406x over previous
//
#include <hip/hip_runtime.h>
#include <cmath>

#define NDOF 7
#define HID  256
#define SPW  8            // samples per workgroup
#define NCOL 64           // 8 primal cols (0..7) + 56 tangent cols (8 + s*7 + d)
#define SWZ(c) (((c) & 7) << 3)

typedef __bf16 bf16x8 __attribute__((ext_vector_type(8)));
typedef float  f32x4  __attribute__((ext_vector_type(4)));

// ws layout (bf16 elems): W1b@0 (65536), W2b@65536, Whb@131072 (48x256), W0b@143360 (256x32 K-padded)
#define OFF_W2 65536
#define OFF_WH 131072
#define OFF_W0 143360
#define WS_TOT 151552

// head-output scratch: [4096 blocks][35 rows][64 cols] f32 — static device global,
// module-allocated (graph-safe, independent of ws_size). Fully rewritten every launch.
#define MAXBLK 4096
__device__ float g_scr[MAXBLK * 35 * 64];

__device__ __forceinline__ float softplus_fast(float x){
    float e = __expf(-fabsf(x));
    return fmaxf(x, 0.0f) + __logf(1.0f + e);
}
__device__ __forceinline__ float sigmoid_fast(float x){
    float e  = __expf(-fabsf(x));
    float rc = 1.0f / (1.0f + e);
    return (x >= 0.0f) ? rc : e * rc;
}
__device__ __forceinline__ float tanh_fast(float y){
    float e2 = __expf(-2.0f * fabsf(y));
    float t  = (1.0f - e2) / (1.0f + e2);
    return (y >= 0.0f) ? t : -t;
}

__global__ void convert_weights(const float* __restrict__ W1, const float* __restrict__ W2,
                                const float* __restrict__ Wg, const float* __restrict__ Wld,
                                const float* __restrict__ Wlt, const float* __restrict__ W0,
                                __bf16* __restrict__ ws)
{
    int i = blockIdx.x * 256 + threadIdx.x;
    if (i < OFF_W2)        ws[i] = (__bf16)W1[i];
    else if (i < OFF_WH)   ws[i] = (__bf16)W2[i - OFF_W2];
    else if (i < OFF_W0) {
        int j = i - OFF_WH;
        int r = j >> 8, k = j & 255;
        float v = 0.0f;
        if (r < 7)       v = Wg [r * HID + k];
        else if (r < 14) v = Wld[(r - 7) * HID + k];
        else if (r < 35) v = Wlt[(r - 14) * HID + k];
        ws[i] = (__bf16)v;
    } else if (i < WS_TOT) {
        int j = i - OFF_W0;
        int r = j >> 5, k = j & 31;
        ws[i] = (__bf16)((k < 7) ? W0[r * 7 + k] : 0.0f);
    }
}

// one MLP layer (R6 config: acc[4][4]=64 regs, unroll 2, (256,4)): acc = Wb @ Xs,
// softplus/sigmoid-tangent epilogue, write back to Xs.
// unroll 2 ONLY — unroll 4 spills acc to scratch (R4/R5: 1.1 GB scratch traffic).
// No N-split — halving MFMA density per latency window regressed 1.55x (R9).
template<int KK>
__device__ __forceinline__ void mlp_layer(
    const __bf16* __restrict__ Wb, int astride, const float* __restrict__ bp,
    __bf16* Xs, int w, int lo, int hi, const int* srcl, bool prim)
{
    f32x4 acc[4][4];
    #pragma unroll
    for (int mi = 0; mi < 4; ++mi)
        #pragma unroll
        for (int ni = 0; ni < 4; ++ni) acc[mi][ni] = (f32x4){0.f,0.f,0.f,0.f};

    #pragma unroll 2
    for (int kk = 0; kk < KK; ++kk){
        const int k0 = kk * 32 + hi * 8;
        bf16x8 a[4], bfr[4];
        #pragma unroll
        for (int mi = 0; mi < 4; ++mi)
            a[mi] = *reinterpret_cast<const bf16x8*>(Wb + (w * 64 + mi * 16 + lo) * astride + k0);
        #pragma unroll
        for (int ni = 0; ni < 4; ++ni){
            int col = ni * 16 + lo;
            bfr[ni] = *reinterpret_cast<const bf16x8*>(Xs + col * HID + (k0 ^ SWZ(col)));
        }
        #pragma unroll
        for (int mi = 0; mi < 4; ++mi)
            #pragma unroll
            for (int ni = 0; ni < 4; ++ni)
                acc[mi][ni] = __builtin_amdgcn_mfma_f32_16x16x32_bf16(a[mi], bfr[ni], acc[mi][ni], 0, 0, 0);
    }
    __syncthreads();   // all Xs reads complete before overwrite

    #pragma unroll
    for (int mi = 0; mi < 4; ++mi){
        const int row0 = w * 64 + mi * 16 + hi * 4;
        float4 b4 = *reinterpret_cast<const float4*>(bp + row0);
        float h[4], sg[4];
        #pragma unroll
        for (int r = 0; r < 4; ++r){
            float z  = acc[mi][0][r] + ((const float*)&b4)[r];
            float e  = __expf(-fabsf(z));
            float rc = 1.0f / (1.0f + e);
            h[r]  = fmaxf(z, 0.0f) + __logf(1.0f + e);
            sg[r] = (z >= 0.0f) ? rc : e * rc;
        }
        #pragma unroll
        for (int ni = 0; ni < 4; ++ni){
            int col = ni * 16 + lo;
            union { uint2 u2; __bf16 b[4]; } pk;
            #pragma unroll
            for (int r = 0; r < 4; ++r){
                float sgb = __shfl(sg[r], srcl[ni]);
                float v   = (ni == 0 && prim) ? h[r] : sgb * acc[mi][ni][r];
                pk.b[r] = (__bf16)v;
            }
            *reinterpret_cast<uint2*>(Xs + col * HID + (row0 ^ SWZ(col))) = pk.u2;
        }
    }
    __syncthreads();
}

__launch_bounds__(256, 4)
__global__ void dln_main(
    const float* __restrict__ q,
    const float* __restrict__ b0, const float* __restrict__ b1, const float* __restrict__ b2,
    const __bf16* __restrict__ wsb)
{
    __shared__ __align__(16) __bf16 Xs[NCOL * HID];   // 32 KB

    const int tid = threadIdx.x;
    const int w   = tid >> 6;
    const int l   = tid & 63;
    const int lo  = l & 15;
    const int hi  = l >> 4;
    const int s0g = blockIdx.x * SPW;
    const bool prim = (lo < 8);

    int srcl[4];
    #pragma unroll
    for (int ni = 0; ni < 4; ++ni){
        int col  = ni * 16 + lo;
        int s    = (col < 8) ? col : (col - 8) / 7;
        srcl[ni] = (l & ~15) | s;
    }

    // ---- B0 = [q | I]: zero phys k 0..63 of each col (SWZ(7) keeps logical k<32 within 0..63) ----
    {
        int col = tid >> 2, part = tid & 3;
        uint4 z4 = {0,0,0,0};
        *reinterpret_cast<uint4*>(Xs + col * HID + part * 16)     = z4;
        *reinterpret_cast<uint4*>(Xs + col * HID + part * 16 + 8) = z4;
    }
    __syncthreads();
    if (tid < 56){
        int s = tid / 7, d = tid - s * 7;
        Xs[s * HID + (d ^ SWZ(s))] = (__bf16)q[(s0g + s) * NDOF + d];
        int c = 8 + s * 7 + d;
        Xs[c * HID + (d ^ SWZ(c))] = (__bf16)1.0f;
    }
    __syncthreads();

    // ---- 3 MLP layers ----
    mlp_layer<1>(wsb + OFF_W0, 32,  b0, Xs, w, lo, hi, srcl, prim);
    mlp_layer<8>(wsb,          HID, b1, Xs, w, lo, hi, srcl, prim);
    mlp_layer<8>(wsb + OFF_W2, HID, b2, Xs, w, lo, hi, srcl, prim);

    // ---- heads: [48x256] @ X -> g_scr[block][row][col] (waves 0..2), then done ----
    if (w < 3){
        f32x4 hacc[4];
        #pragma unroll
        for (int ni = 0; ni < 4; ++ni) hacc[ni] = (f32x4){0.f,0.f,0.f,0.f};
        const __bf16* Wh = wsb + OFF_WH;
        #pragma unroll 2
        for (int kk = 0; kk < 8; ++kk){
            const int k0 = kk * 32 + hi * 8;
            bf16x8 a = *reinterpret_cast<const bf16x8*>(Wh + (w * 16 + lo) * HID + k0);
            #pragma unroll
            for (int ni = 0; ni < 4; ++ni){
                int col = ni * 16 + lo;
                bf16x8 bfr = *reinterpret_cast<const bf16x8*>(Xs + col * HID + (k0 ^ SWZ(col)));
                hacc[ni] = __builtin_amdgcn_mfma_f32_16x16x32_bf16(a, bfr, hacc[ni], 0, 0, 0);
            }
        }
        float* dst = g_scr + (size_t)blockIdx.x * (35 * 64);
        #pragma unroll
        for (int ni = 0; ni < 4; ++ni)
            #pragma unroll
            for (int r = 0; r < 4; ++r){
                int row = w * 16 + hi * 4 + r;
                if (row < 35) dst[row * 64 + ni * 16 + lo] = hacc[ni][r];
            }
    }
}

// ---- tail kernel: one block per 8 samples; identical 49-lane-parallel tail, but
// at high occupancy (12.9 KB LDS, low VGPR) where its latency chains are hidden. ----
__launch_bounds__(256)
__global__ void dln_tail(
    const float* __restrict__ qd, const float* __restrict__ qdd,
    const float* __restrict__ bg, const float* __restrict__ bld, const float* __restrict__ blt,
    const float* __restrict__ fd, const float* __restrict__ fc,
    const float* __restrict__ fs, const float* __restrict__ fv,
    float* __restrict__ out, int Btot)
{
    __shared__ float SCRT[64 * 41];     // [col][row], padded stride 41
    __shared__ float SGb[8 * 8];
    __shared__ float UV [8 * 16];
    __shared__ float LL [8 * 52];

    const int tid = threadIdx.x;
    const int w   = tid >> 6;
    const int l   = tid & 63;
    const int s0g = blockIdx.x * SPW;

    // load head outputs, transposing [row][col] -> SCRT[col][row]
    {
        const float* src = g_scr + (size_t)blockIdx.x * (35 * 64);
        for (int i = tid; i < 35 * 64; i += 256){
            int row = i >> 6, col = i & 63;
            SCRT[col * 41 + row] = src[i];
        }
    }
    __syncthreads();

    const bool t49 = (l < 49);
    const int  tt  = t49 ? l : 0;
    const int  r   = tt / 7;
    const int  c   = tt - r * 7;
    const int  B   = Btot;
    float* oH = out + (size_t)B * 7;
    float* oC = out + (size_t)B * 56;
    float* oG = out + (size_t)B * 63;
    float* oF = out + (size_t)B * 70;
    float* oL = out + (size_t)B * 77;

    for (int p = 0; p < 2; ++p){
        const int ss = p * 4 + w;
        const int Sg = __builtin_amdgcn_readfirstlane(s0g + ss);

        // qdv[] only indexed with compile-time constants (unrolled loops);
        // lane-dependent values are direct global loads (L1-cached). (rule #20)
        float qdv[7];
        #pragma unroll
        for (int d = 0; d < 7; ++d) qdv[d] = qd[Sg * 7 + d];
        const float qd_r  = qd [Sg * 7 + r];
        const float qd_c  = qd [Sg * 7 + c];
        const float qdd_c = qdd[Sg * 7 + c];

        const int colP  = ss * 41;
        const int tri_r = (r * (r - 1)) >> 1;

        float ldraw = SCRT[colP + 7 + r] + bld[r];
        float sg_r  = sigmoid_fast(ldraw);
        float Lrr   = softplus_fast(ldraw) + 1e-3f;
        float Lij   = 0.f;
        if (c < r)       Lij = SCRT[colP + 14 + tri_r + c] + blt[tri_r + c];
        else if (c == r) Lij = Lrr;

        if (t49)           LL[ss * 52 + tt] = Lij;
        if (t49 && r == c) SGb[ss * 8 + r]  = sg_r;

        // u[b] = sum_a qd_a L[a][b]  (reduce over r, result at r==0 lanes l=c)
        float ux = qd_r * Lij;
        { float xs;
          xs = __shfl(ux, l + 7);  ux += (r + 1 <= 6) ? xs : 0.f;
          xs = __shfl(ux, l + 14); ux += (r + 2 <= 6) ? xs : 0.f;
          xs = __shfl(ux, l + 28); ux += (r + 4 <= 6) ? xs : 0.f; }
        if (t49 && r == 0) UV[ss * 16 + c] = ux;

        asm volatile("s_waitcnt lgkmcnt(0)" ::: "memory");
        __builtin_amdgcn_sched_barrier(0);

        float sgv[7];
        #pragma unroll
        for (int jj = 0; jj < 7; ++jj) sgv[jj] = SGb[ss * 8 + jj];

        // v[r][c] = sum_jj qd_jj LDQ(jj, r, c)
        const int colT = (8 + ss * 7 + c) * 41;
        float v = 0.f;
        #pragma unroll
        for (int jj = 0; jj < 7; ++jj){
            constexpr int triT[7] = {0,0,1,3,6,10,15};
            int   row = (jj == r) ? (7 + jj) : (14 + triT[jj] + r);
            float x   = SCRT[colT + row];
            float val = (jj == r) ? sgv[jj] * x : ((jj > r) ? x : 0.f);
            v = fmaf(qdv[jj], val, v);
        }

        // ldt[r][c] = sum_cc LDQ(r, c, cc) qd_cc
        {
            int   rowF   = (r == c) ? (7 + r) : (14 + tri_r + c);
            float scaleF = (r == c) ? sg_r : ((r > c) ? 1.f : 0.f);
            float acc2 = 0.f;
            #pragma unroll
            for (int cc = 0; cc < 7; ++cc)
                acc2 = fmaf(qdv[cc], SCRT[(8 + ss * 7 + cc) * 41 + rowF], acc2);
            float ldt = acc2 * scaleF;

            // w2[k=r] = sum_c v[r][c] qd_c  (reduce over c, result at c==0 lanes l=7r)
            float wx = v * qd_c;
            { float xs;
              xs = __shfl(wx, l + 1); wx += (c + 1 <= 6) ? xs : 0.f;
              xs = __shfl(wx, l + 2); wx += (c + 2 <= 6) ? xs : 0.f;
              xs = __shfl(wx, l + 4); wx += (c + 4 <= 6) ? xs : 0.f; }
            if (t49 && c == 0) UV[ss * 16 + 8 + r] = wx;

            asm volatile("s_waitcnt lgkmcnt(0)" ::: "memory");
            __builtin_amdgcn_sched_barrier(0);

            float u_c  = UV[ss * 16 + c];
            float u_r  = UV[ss * 16 + r];
            float w2_c = UV[ss * 16 + 8 + c];

            // qh[i=c] = sum_m u[m] v[m][i]  (reduce over r, result at r==0 lanes l=c)
            float qx = u_r * v;
            { float xs;
              xs = __shfl(qx, l + 7);  qx += (r + 1 <= 6) ? xs : 0.f;
              xs = __shfl(qx, l + 14); qx += (r + 2 <= 6) ? xs : 0.f;
              xs = __shfl(qx, l + 28); qx += (r + 4 <= 6) ? xs : 0.f; }

            // c1[i=r] = sum_k L[r][k] w2[k] + ldt[r][k] u[k]  (reduce over c)
            float cx = Lij * w2_c + ldt * u_c;
            { float xs;
              xs = __shfl(cx, l + 1); cx += (c + 1 <= 6) ? xs : 0.f;
              xs = __shfl(cx, l + 2); cx += (c + 2 <= 6) ? xs : 0.f;
              xs = __shfl(cx, l + 4); cx += (c + 4 <= 6) ? xs : 0.f; }

            // hm[r][c] = sum_k L[r][k] L[c][k]
            float hm = 0.f;
            #pragma unroll
            for (int k = 0; k < 7; ++k)
                hm = fmaf(LL[ss * 52 + r * 7 + k], LL[ss * 52 + c * 7 + k], hm);

            // tau partial: sum_j hm[r][j] qdd_j  (reduce over c)
            float tx = hm * qdd_c;
            { float xs;
              xs = __shfl(tx, l + 1); tx += (c + 1 <= 6) ? xs : 0.f;
              xs = __shfl(tx, l + 2); tx += (c + 2 <= 6) ? xs : 0.f;
              xs = __shfl(tx, l + 4); tx += (c + 4 <= 6) ? xs : 0.f; }

            float qh_r = __shfl(qx, r);      // qh[r] lives at lane l=r
            float gv   = SCRT[colP + r] + bg[r];
            float fvc  = fmaxf(fv[r], 1e-3f);
            float tf   = (fc[r] + fs[r] * __expf(-qd_r * qd_r / fvc)) * tanh_fast(100.0f * qd_r) + fd[r] * qd_r;
            float cfin = cx - qh_r;
            float tau  = cfin + gv + tf + tx;

            if (t49) oH[(size_t)Sg * 49 + tt] = hm;
            if (t49 && c == 0){
                out[Sg * 7 + r] = tau;
                oC[Sg * 7 + r]  = cfin;
                oG[Sg * 7 + r]  = gv;
                oF[Sg * 7 + r]  = tf;
                oL[Sg * 7 + r]  = ldraw;
            }
        }
    }
}

extern "C" void kernel_launch(void* const* d_in, const int* in_sizes, int n_in,
                              void* d_out, int out_size, void* d_ws, size_t ws_size,
                              hipStream_t stream) {
    const float* q   = (const float*)d_in[0];
    const float* qd  = (const float*)d_in[1];
    const float* qdd = (const float*)d_in[2];
    const float* W0  = (const float*)d_in[3];
    const float* b0  = (const float*)d_in[4];
    const float* W1  = (const float*)d_in[5];
    const float* b1  = (const float*)d_in[6];
    const float* W2  = (const float*)d_in[7];
    const float* b2  = (const float*)d_in[8];
    const float* Wg  = (const float*)d_in[9];
    const float* bg  = (const float*)d_in[10];
    const float* Wld = (const float*)d_in[11];
    const float* bld = (const float*)d_in[12];
    const float* Wlt = (const float*)d_in[13];
    const float* blt = (const float*)d_in[14];
    const float* fd  = (const float*)d_in[15];
    const float* fc  = (const float*)d_in[16];
    const float* fs  = (const float*)d_in[17];
    const float* fv  = (const float*)d_in[18];

    const int Btot = in_sizes[0] / NDOF;      // 32768
    const int nblk = Btot / SPW;              // 4096 (fits MAXBLK)
    __bf16* wsb = (__bf16*)d_ws;

    convert_weights<<<dim3(WS_TOT / 256), dim3(256), 0, stream>>>(W1, W2, Wg, Wld, Wlt, W0, wsb);
    dln_main<<<dim3(nblk), dim3(256), 0, stream>>>(q, b0, b1, b2, wsb);
    dln_tail<<<dim3(nblk), dim3(256), 0, stream>>>(qd, qdd, bg, bld, blt,
                                                   fd, fc, fs, fv,
                                                   (float*)d_out, Btot);
}

// Round 11
// 233.531 us; speedup vs baseline: 1.5352x; 1.1452x over previous
//
#include <hip/hip_runtime.h>
#include <cmath>

#define NDOF 7
#define HID  256
#define SPW  16           // samples per workgroup
#define NCOL 128          // 16 primal cols (0..15) + 112 tangent cols (16 + s*7 + d)
#define SWZ(c) (((c) & 7) << 3)

typedef __bf16 bf16x8 __attribute__((ext_vector_type(8)));
typedef float  f32x4  __attribute__((ext_vector_type(4)));

// ws layout (bf16 elems): W1b@0 (65536), W2b@65536, Whb@131072 (48x256), W0b@143360 (256x32 K-padded)
#define OFF_W2 65536
#define OFF_WH 131072
#define OFF_W0 143360
#define WS_TOT 151552

__device__ __forceinline__ float softplus_fast(float x){
    float e = __expf(-fabsf(x));
    return fmaxf(x, 0.0f) + __logf(1.0f + e);
}
__device__ __forceinline__ float sigmoid_fast(float x){
    float e  = __expf(-fabsf(x));
    float rc = 1.0f / (1.0f + e);
    return (x >= 0.0f) ? rc : e * rc;
}
__device__ __forceinline__ float tanh_fast(float y){
    float e2 = __expf(-2.0f * fabsf(y));
    float t  = (1.0f - e2) / (1.0f + e2);
    return (y >= 0.0f) ? t : -t;
}

__global__ void convert_weights(const float* __restrict__ W1, const float* __restrict__ W2,
                                const float* __restrict__ Wg, const float* __restrict__ Wld,
                                const float* __restrict__ Wlt, const float* __restrict__ W0,
                                __bf16* __restrict__ ws)
{
    int i = blockIdx.x * 256 + threadIdx.x;
    if (i < OFF_W2)        ws[i] = (__bf16)W1[i];
    else if (i < OFF_WH)   ws[i] = (__bf16)W2[i - OFF_W2];
    else if (i < OFF_W0) {
        int j = i - OFF_WH;
        int r = j >> 8, k = j & 255;
        float v = 0.0f;
        if (r < 7)       v = Wg [r * HID + k];
        else if (r < 14) v = Wld[(r - 7) * HID + k];
        else if (r < 35) v = Wlt[(r - 14) * HID + k];
        ws[i] = (__bf16)v;
    } else if (i < WS_TOT) {
        int j = i - OFF_W0;
        int r = j >> 5, k = j & 31;
        ws[i] = (__bf16)((k < 7) ? W0[r * 7 + k] : 0.0f);
    }
}

// one MLP layer, 128-column tile: acc[4 mi][8 ni] = 128 VGPR, K-loop unroll 1
// (staging 48 + acc 128 must stay under the (256,2) cap — R4/R5 spill lesson).
// Per kk: 32 MFMAs against 4 weight loads + 8 LDS reads — 2x the MFMA density
// per latency window of the SPW=8 version (R9: density is the binding constraint).
template<int KK>
__device__ __forceinline__ void mlp_layer(
    const __bf16* __restrict__ Wb, int astride, const float* __restrict__ bp,
    __bf16* Xs, int w, int lo, int hi, const int* srcl)
{
    f32x4 acc[4][8];
    #pragma unroll
    for (int mi = 0; mi < 4; ++mi)
        #pragma unroll
        for (int ni = 0; ni < 8; ++ni) acc[mi][ni] = (f32x4){0.f,0.f,0.f,0.f};

    #pragma unroll 1
    for (int kk = 0; kk < KK; ++kk){
        const int k0 = kk * 32 + hi * 8;
        bf16x8 a[4], bfr[8];
        #pragma unroll
        for (int mi = 0; mi < 4; ++mi)
            a[mi] = *reinterpret_cast<const bf16x8*>(Wb + (w * 64 + mi * 16 + lo) * astride + k0);
        #pragma unroll
        for (int ni = 0; ni < 8; ++ni){
            int col = ni * 16 + lo;
            bfr[ni] = *reinterpret_cast<const bf16x8*>(Xs + col * HID + (k0 ^ SWZ(col)));
        }
        #pragma unroll
        for (int mi = 0; mi < 4; ++mi)
            #pragma unroll
            for (int ni = 0; ni < 8; ++ni)
                acc[mi][ni] = __builtin_amdgcn_mfma_f32_16x16x32_bf16(a[mi], bfr[ni], acc[mi][ni], 0, 0, 0);
    }
    __syncthreads();   // all Xs reads complete before overwrite

    #pragma unroll
    for (int mi = 0; mi < 4; ++mi){
        const int row0 = w * 64 + mi * 16 + hi * 4;
        float4 b4 = *reinterpret_cast<const float4*>(bp + row0);
        float h[4], sg[4];
        #pragma unroll
        for (int r = 0; r < 4; ++r){
            // ni==0 tile is all-primal: every lane's z is a real pre-activation
            float z  = acc[mi][0][r] + ((const float*)&b4)[r];
            float e  = __expf(-fabsf(z));
            float rc = 1.0f / (1.0f + e);
            h[r]  = fmaxf(z, 0.0f) + __logf(1.0f + e);
            sg[r] = (z >= 0.0f) ? rc : e * rc;
        }
        #pragma unroll
        for (int ni = 0; ni < 8; ++ni){
            int col = ni * 16 + lo;
            union { uint2 u2; __bf16 b[4]; } pk;
            #pragma unroll
            for (int r = 0; r < 4; ++r){
                float sgb = __shfl(sg[r], srcl[ni]);
                float v   = (ni == 0) ? h[r] : sgb * acc[mi][ni][r];
                pk.b[r] = (__bf16)v;
            }
            *reinterpret_cast<uint2*>(Xs + col * HID + (row0 ^ SWZ(col))) = pk.u2;
        }
    }
    __syncthreads();
}

__launch_bounds__(256, 2)
__global__ void dln_main(
    const float* __restrict__ q,  const float* __restrict__ qd, const float* __restrict__ qdd,
    const float* __restrict__ b0, const float* __restrict__ b1, const float* __restrict__ b2,
    const float* __restrict__ bg, const float* __restrict__ bld, const float* __restrict__ blt,
    const float* __restrict__ fd, const float* __restrict__ fc,
    const float* __restrict__ fs, const float* __restrict__ fv,
    const __bf16* __restrict__ wsb,
    float* __restrict__ out, int Btot)
{
    __shared__ __align__(16) unsigned char LDSB[65536];
    __bf16* Xs = (__bf16*)LDSB;

    const int tid = threadIdx.x;
    const int w   = tid >> 6;
    const int l   = tid & 63;
    const int lo  = l & 15;
    const int hi  = l >> 4;
    const int s0g = blockIdx.x * SPW;

    int srcl[8];
    #pragma unroll
    for (int ni = 0; ni < 8; ++ni){
        int col  = ni * 16 + lo;
        int s    = (col < 16) ? col : (col - 16) / 7;
        srcl[ni] = (l & ~15) | s;
    }

    // ---- B0 = [q | I]: zero phys k 0..63 of each of the 128 cols ----
    {
        int col = tid >> 1, half = tid & 1;
        uint4 z4 = {0,0,0,0};
        __bf16* base = Xs + col * HID + half * 32;
        *reinterpret_cast<uint4*>(base)      = z4;
        *reinterpret_cast<uint4*>(base + 8)  = z4;
        *reinterpret_cast<uint4*>(base + 16) = z4;
        *reinterpret_cast<uint4*>(base + 24) = z4;
    }
    __syncthreads();
    if (tid < SPW * NDOF){   // 112
        int s = tid / 7, d = tid - s * 7;
        Xs[s * HID + (d ^ SWZ(s))] = (__bf16)q[(s0g + s) * NDOF + d];
        int c = 16 + s * 7 + d;
        Xs[c * HID + (d ^ SWZ(c))] = (__bf16)1.0f;
    }
    __syncthreads();

    // ---- 3 MLP layers ----
    mlp_layer<1>(wsb + OFF_W0, 32,  b0, Xs, w, lo, hi, srcl);
    mlp_layer<8>(wsb,          HID, b1, Xs, w, lo, hi, srcl);
    mlp_layer<8>(wsb + OFF_W2, HID, b2, Xs, w, lo, hi, srcl);

    // ---- heads: [48x256] @ X -> registers (waves 0..2) ----
    f32x4 hacc[8];
    #pragma unroll
    for (int ni = 0; ni < 8; ++ni) hacc[ni] = (f32x4){0.f,0.f,0.f,0.f};
    if (w < 3){
        const __bf16* Wh = wsb + OFF_WH;
        #pragma unroll 2
        for (int kk = 0; kk < 8; ++kk){
            const int k0 = kk * 32 + hi * 8;
            bf16x8 a = *reinterpret_cast<const bf16x8*>(Wh + (w * 16 + lo) * HID + k0);
            #pragma unroll
            for (int ni = 0; ni < 8; ++ni){
                int col = ni * 16 + lo;
                bf16x8 bfr = *reinterpret_cast<const bf16x8*>(Xs + col * HID + (k0 ^ SWZ(col)));
                hacc[ni] = __builtin_amdgcn_mfma_f32_16x16x32_bf16(a, bfr, hacc[ni], 0, 0, 0);
            }
        }
    }
    __syncthreads();            // Xs fully read; region becomes SCRT + tail scratch

    // SCRT[col][row], stride 41 f32 (transposed head outputs), 128 cols
    float* SCRT = (float*)LDSB;                     // 128*41*4 = 20992 B
    float* SGb  = (float*)(LDSB + 21248);           // [16][8]   sigmoid(Ld_raw)
    float* UV   = (float*)(LDSB + 21760);           // [16][16]: u@0..6, w2@8..14
    float* LL   = (float*)(LDSB + 22784);           // [16][52]: L matrix rows

    if (w < 3){
        #pragma unroll
        for (int ni = 0; ni < 8; ++ni)
            #pragma unroll
            for (int r = 0; r < 4; ++r){
                int row = w * 16 + hi * 4 + r;
                if (row < 35) SCRT[(ni * 16 + lo) * 41 + row] = hacc[ni][r];
            }
    }
    __syncthreads();

    // ---- analytic tail: lane (r,c) parallel, 49 active lanes/wave, 4 samples/wave ----
    const bool t49 = (l < 49);
    const int  tt  = t49 ? l : 0;
    const int  r   = tt / 7;
    const int  c   = tt - r * 7;
    const int  B   = Btot;
    float* oH = out + (size_t)B * 7;
    float* oC = out + (size_t)B * 56;
    float* oG = out + (size_t)B * 63;
    float* oF = out + (size_t)B * 70;
    float* oL = out + (size_t)B * 77;

    for (int p = 0; p < 4; ++p){
        const int ss = p * 4 + w;
        const int Sg = __builtin_amdgcn_readfirstlane(s0g + ss);

        // qdv[] only indexed with compile-time constants (unrolled loops);
        // lane-dependent values are direct global loads (L1-cached). (rule #20)
        float qdv[7];
        #pragma unroll
        for (int d = 0; d < 7; ++d) qdv[d] = qd[Sg * 7 + d];
        const float qd_r  = qd [Sg * 7 + r];
        const float qd_c  = qd [Sg * 7 + c];
        const float qdd_c = qdd[Sg * 7 + c];

        const int colP  = ss * 41;
        const int tri_r = (r * (r - 1)) >> 1;

        float ldraw = SCRT[colP + 7 + r] + bld[r];
        float sg_r  = sigmoid_fast(ldraw);
        float Lrr   = softplus_fast(ldraw) + 1e-3f;
        float Lij   = 0.f;
        if (c < r)       Lij = SCRT[colP + 14 + tri_r + c] + blt[tri_r + c];
        else if (c == r) Lij = Lrr;

        if (t49)           LL[ss * 52 + tt] = Lij;
        if (t49 && r == c) SGb[ss * 8 + r]  = sg_r;

        // u[b] = sum_a qd_a L[a][b]  (reduce over r, result at r==0 lanes l=c)
        float ux = qd_r * Lij;
        { float xs;
          xs = __shfl(ux, l + 7);  ux += (r + 1 <= 6) ? xs : 0.f;
          xs = __shfl(ux, l + 14); ux += (r + 2 <= 6) ? xs : 0.f;
          xs = __shfl(ux, l + 28); ux += (r + 4 <= 6) ? xs : 0.f; }
        if (t49 && r == 0) UV[ss * 16 + c] = ux;

        asm volatile("s_waitcnt lgkmcnt(0)" ::: "memory");
        __builtin_amdgcn_sched_barrier(0);

        float sgv[7];
        #pragma unroll
        for (int jj = 0; jj < 7; ++jj) sgv[jj] = SGb[ss * 8 + jj];

        // v[r][c] = sum_jj qd_jj LDQ(jj, r, c)
        const int colT = (16 + ss * 7 + c) * 41;
        float v = 0.f;
        #pragma unroll
        for (int jj = 0; jj < 7; ++jj){
            constexpr int triT[7] = {0,0,1,3,6,10,15};
            int   row = (jj == r) ? (7 + jj) : (14 + triT[jj] + r);
            float x   = SCRT[colT + row];
            float val = (jj == r) ? sgv[jj] * x : ((jj > r) ? x : 0.f);
            v = fmaf(qdv[jj], val, v);
        }

        // ldt[r][c] = sum_cc LDQ(r, c, cc) qd_cc
        {
            int   rowF   = (r == c) ? (7 + r) : (14 + tri_r + c);
            float scaleF = (r == c) ? sg_r : ((r > c) ? 1.f : 0.f);
            float acc2 = 0.f;
            #pragma unroll
            for (int cc = 0; cc < 7; ++cc)
                acc2 = fmaf(qdv[cc], SCRT[(16 + ss * 7 + cc) * 41 + rowF], acc2);
            float ldt = acc2 * scaleF;

            // w2[k=r] = sum_c v[r][c] qd_c  (reduce over c, result at c==0 lanes l=7r)
            float wx = v * qd_c;
            { float xs;
              xs = __shfl(wx, l + 1); wx += (c + 1 <= 6) ? xs : 0.f;
              xs = __shfl(wx, l + 2); wx += (c + 2 <= 6) ? xs : 0.f;
              xs = __shfl(wx, l + 4); wx += (c + 4 <= 6) ? xs : 0.f; }
            if (t49 && c == 0) UV[ss * 16 + 8 + r] = wx;

            asm volatile("s_waitcnt lgkmcnt(0)" ::: "memory");
            __builtin_amdgcn_sched_barrier(0);

            float u_c  = UV[ss * 16 + c];
            float u_r  = UV[ss * 16 + r];
            float w2_c = UV[ss * 16 + 8 + c];

            // qh[i=c] = sum_m u[m] v[m][i]  (reduce over r, result at r==0 lanes l=c)
            float qx = u_r * v;
            { float xs;
              xs = __shfl(qx, l + 7);  qx += (r + 1 <= 6) ? xs : 0.f;
              xs = __shfl(qx, l + 14); qx += (r + 2 <= 6) ? xs : 0.f;
              xs = __shfl(qx, l + 28); qx += (r + 4 <= 6) ? xs : 0.f; }

            // c1[i=r] = sum_k L[r][k] w2[k] + ldt[r][k] u[k]  (reduce over c)
            float cx = Lij * w2_c + ldt * u_c;
            { float xs;
              xs = __shfl(cx, l + 1); cx += (c + 1 <= 6) ? xs : 0.f;
              xs = __shfl(cx, l + 2); cx += (c + 2 <= 6) ? xs : 0.f;
              xs = __shfl(cx, l + 4); cx += (c + 4 <= 6) ? xs : 0.f; }

            // hm[r][c] = sum_k L[r][k] L[c][k]
            float hm = 0.f;
            #pragma unroll
            for (int k = 0; k < 7; ++k)
                hm = fmaf(LL[ss * 52 + r * 7 + k], LL[ss * 52 + c * 7 + k], hm);

            // tau partial: sum_j hm[r][j] qdd_j  (reduce over c)
            float tx = hm * qdd_c;
            { float xs;
              xs = __shfl(tx, l + 1); tx += (c + 1 <= 6) ? xs : 0.f;
              xs = __shfl(tx, l + 2); tx += (c + 2 <= 6) ? xs : 0.f;
              xs = __shfl(tx, l + 4); tx += (c + 4 <= 6) ? xs : 0.f; }

            float qh_r = __shfl(qx, r);      // qh[r] lives at lane l=r
            float gv   = SCRT[colP + r] + bg[r];
            float fvc  = fmaxf(fv[r], 1e-3f);
            float tf   = (fc[r] + fs[r] * __expf(-qd_r * qd_r / fvc)) * tanh_fast(100.0f * qd_r) + fd[r] * qd_r;
            float cfin = cx - qh_r;
            float tau  = cfin + gv + tf + tx;

            if (t49) oH[(size_t)Sg * 49 + tt] = hm;
            if (t49 && c == 0){
                out[Sg * 7 + r] = tau;
                oC[Sg * 7 + r]  = cfin;
                oG[Sg * 7 + r]  = gv;
                oF[Sg * 7 + r]  = tf;
                oL[Sg * 7 + r]  = ldraw;
            }
        }
    }
}

extern "C" void kernel_launch(void* const* d_in, const int* in_sizes, int n_in,
                              void* d_out, int out_size, void* d_ws, size_t ws_size,
                              hipStream_t stream) {
    const float* q   = (const float*)d_in[0];
    const float* qd  = (const float*)d_in[1];
    const float* qdd = (const float*)d_in[2];
    const float* W0  = (const float*)d_in[3];
    const float* b0  = (const float*)d_in[4];
    const float* W1  = (const float*)d_in[5];
    const float* b1  = (const float*)d_in[6];
    const float* W2  = (const float*)d_in[7];
    const float* b2  = (const float*)d_in[8];
    const float* Wg  = (const float*)d_in[9];
    const float* bg  = (const float*)d_in[10];
    const float* Wld = (const float*)d_in[11];
    const float* bld = (const float*)d_in[12];
    const float* Wlt = (const float*)d_in[13];
    const float* blt = (const float*)d_in[14];
    const float* fd  = (const float*)d_in[15];
    const float* fc  = (const float*)d_in[16];
    const float* fs  = (const float*)d_in[17];
    const float* fv  = (const float*)d_in[18];

    const int Btot = in_sizes[0] / NDOF;      // 32768
    __bf16* wsb = (__bf16*)d_ws;

    convert_weights<<<dim3(WS_TOT / 256), dim3(256), 0, stream>>>(W1, W2, Wg, Wld, Wlt, W0, wsb);
    dln_main<<<dim3(Btot / SPW), dim3(256), 0, stream>>>(q, qd, qdd, b0, b1, b2,
                                                         bg, bld, blt,
                                                         fd, fc, fs, fv,
                                                         wsb, (float*)d_out, Btot);
}